// Round 2
// baseline (429.128 us; speedup 1.0000x reference)
//
#include <hip/hip_runtime.h>

// LocalConnectivity: out[i][j] = sum_{1<=|dx|+|dy|<=5} w_{|dx|+|dy|} * s[(i+dx)&4095][(j+dy)&4095]
// w_d = exp(-d/2) = r^d  =>  separable: w_{|dx|+|dy|} = r^{|dx|} * r^{|dy|}
//
// out[i][j] = sum_{dx=-5..5} r^{|dx|} * H_{5-|dx|}[i+dx][j] - s[i][j]
// H_k[t][j] = sum_{|dy|<=k} r^{|dy|} s[t][j+dy], built incrementally (5 add + 5 fma).
//
// R2 changes vs R1 (latency-bound, Occupancy 9.5%, VALUBusy 13%):
//  - 256-thread blocks, RCHUNK 34->12  => 1368 blocks / 5472 waves (~21/CU) vs 1936
//  - __launch_bounds__(256,4) caps VGPR<=128 => 4 waves/SIMD capacity
//  - explicit next-row prefetch keeps >=5 loads in flight per wave

#define GH 4096
#define GW 4096
#define GMASK 4095
#define RCHUNK 12   // output rows per block; reads RCHUNK+10 = 22 = 2*11 rows
#define NITER 2

__global__ __launch_bounds__(256, 4)
void diamond_stencil(const float* __restrict__ s, const float* __restrict__ w,
                     float* __restrict__ out)
{
    const int tid   = threadIdx.x;
    const int strip = blockIdx.x;            // 0..3   -> 1024-wide column strip
    const int chunk = blockIdx.y;            // 0..341 -> 12-row chunk
    const int j0 = strip * 1024 + tid * 4;   // first of this thread's 4 columns
    const int t0 = chunk * RCHUNK;           // first output row of this chunk

    // wrapped column offsets (elements); all float4 bases stay 16B-aligned
    const int cm5 = (j0 - 5) & GMASK;
    const int cm4 = (j0 - 4) & GMASK;
    const int cp4 = (j0 + 4) & GMASK;
    const int cp8 = (j0 + 8) & GMASK;

    float wv[6];
    wv[0] = 1.0f;
#pragma unroll
    for (int d = 1; d <= 5; ++d) wv[d] = w[d - 1];   // exp(-d/2)

    // ring of 11 accumulators x 4 columns; slot(o) = (o - t0) mod 11
    float acc[11][4];
#pragma unroll
    for (int i = 0; i < 11; ++i)
#pragma unroll
        for (int c = 0; c < 4; ++c) acc[i][c] = 0.0f;

    // preload first input row (t0 - 5)
    float  curL, curR;
    float4 curA, curB, curC;
    {
        const float* srow = s + (((t0 - 5) & GMASK) << 12);
        curL = srow[cm5];
        curA = *(const float4*)(srow + cm4);
        curB = *(const float4*)(srow + j0);
        curC = *(const float4*)(srow + cp4);
        curR = srow[cp8];
    }

#pragma unroll 1
    for (int it = 0; it < NITER; ++it) {
        const int tbase = t0 - 5 + it * 11;
#pragma unroll
        for (int ph = 0; ph < 11; ++ph) {
            // ---- prefetch row t+1 (overshoot on last phase is harmless, wraps) ----
            const int tn = tbase + ph + 1;
            const float* nrow = s + ((tn & GMASK) << 12);
            const float  nL = nrow[cm5];
            const float4 nA = *(const float4*)(nrow + cm4);
            const float4 nB = *(const float4*)(nrow + j0);
            const float4 nC = *(const float4*)(nrow + cp4);
            const float  nR = nrow[cp8];

            // ---- compute with current row t = tbase + ph ----
            float v[14];
            v[0] = curL;
            v[1] = curA.x; v[2]  = curA.y; v[3]  = curA.z; v[4]  = curA.w;
            v[5] = curB.x; v[6]  = curB.y; v[7]  = curB.z; v[8]  = curB.w;
            v[9] = curC.x; v[10] = curC.y; v[11] = curC.z; v[12] = curC.w;
            v[13] = curR;

#pragma unroll
            for (int c = 0; c < 4; ++c) {
                const float ctr = v[5 + c];
                float Hs[6];
                Hs[0] = ctr;
#pragma unroll
                for (int k = 1; k <= 5; ++k)
                    Hs[k] = Hs[k - 1] + wv[k] * (v[5 + c - k] + v[5 + c + k]);

                // scatter: row t contributes to output rows o = t+d, d = -5..5
                // slot(o) = (o - t0) mod 11 = (ph + d + 6) mod 11   (static)
                acc[(ph + 6) % 11][c] += Hs[5] - ctr;       // d = 0 (center removed)
#pragma unroll
                for (int d = 1; d <= 5; ++d) {
                    const float contrib = wv[d] * Hs[5 - d];
                    acc[(ph + d + 6) % 11][c] += contrib;   // d = +d
                    acc[(ph - d + 6) % 11][c] += contrib;   // d = -d
                }
            }

            // ---- output row o = t - 5 is complete (last contributor is t) ----
            {
                const int o  = tbase + ph - 5;
                const int sl = (ph + 1) % 11;               // = (o - t0) mod 11
                if (o >= t0 && o < GH) {
                    float4 r;
                    r.x = acc[sl][0]; r.y = acc[sl][1];
                    r.z = acc[sl][2]; r.w = acc[sl][3];
                    *(float4*)(out + ((size_t)o << 12) + j0) = r;
                }
                // always clear: slot is recycled for row o+11 starting next input row
                acc[sl][0] = 0.0f; acc[sl][1] = 0.0f;
                acc[sl][2] = 0.0f; acc[sl][3] = 0.0f;
            }

            // ---- rotate prefetched row into current ----
            curL = nL; curA = nA; curB = nB; curC = nC; curR = nR;
        }
    }
}

extern "C" void kernel_launch(void* const* d_in, const int* in_sizes, int n_in,
                              void* d_out, int out_size, void* d_ws, size_t ws_size,
                              hipStream_t stream)
{
    const float* s = (const float*)d_in[0];   // grid_spikes [4096*4096] f32
    const float* w = (const float*)d_in[1];   // distance_weights [5] f32
    float* out = (float*)d_out;               // [4096*4096] f32

    dim3 grid(4, (GH + RCHUNK - 1) / RCHUNK);  // 4 strips x 342 chunks = 1368 blocks
    dim3 block(256);
    diamond_stencil<<<grid, block, 0, stream>>>(s, w, out);
}

// Round 3
// 161.218 us; speedup vs baseline: 2.6618x; 2.6618x over previous
//
#include <hip/hip_runtime.h>

// LocalConnectivity: out[i][j] = sum_{1<=|dx|+|dy|<=5} w_{|dx|+|dy|} * s[(i+dx)&4095][(j+dy)&4095]
// w_d = exp(-d/2) = r^d  =>  separable: w_{|dx|+|dy|} = r^{|dx|} * r^{|dy|}
//
// out[i][j] = sum_{dx=-5..5} r^{|dx|} * H_{5-|dx|}[i+dx][j] - s[i][j]
// H_k[t][j] = sum_{|dy|<=k} r^{|dy|} s[t][j+dy], built incrementally (5 add + 5 fma).
//
// R3 vs R2: the (256,4) launch-bounds cap spilled the acc ring to scratch
// (WRITE_SIZE 65->569 MB). Remove the cap (compiler ~140-160 VGPR, 3 waves/SIMD,
// no spill), keep RCHUNK=12 grid parallelism (2736 blocks / 5472 waves) and the
// 1-row prefetch. 128-thread blocks pack 6/CU at 12-wave capacity.

#define GH 4096
#define GW 4096
#define GMASK 4095
#define RCHUNK 12   // output rows per block; reads RCHUNK+10 = 22 = 2*11 rows (no waste)
#define NITER 2

__global__ __launch_bounds__(128)
void diamond_stencil(const float* __restrict__ s, const float* __restrict__ w,
                     float* __restrict__ out)
{
    const int tid   = threadIdx.x;
    const int strip = blockIdx.x;            // 0..7   -> 512-wide column strip
    const int chunk = blockIdx.y;            // 0..341 -> 12-row chunk
    const int j0 = strip * 512 + tid * 4;    // first of this thread's 4 columns
    const int t0 = chunk * RCHUNK;           // first output row of this chunk

    // wrapped column offsets (elements); all float4 bases stay 16B-aligned
    const int cm5 = (j0 - 5) & GMASK;
    const int cm4 = (j0 - 4) & GMASK;
    const int cp4 = (j0 + 4) & GMASK;
    const int cp8 = (j0 + 8) & GMASK;

    float wv[6];
    wv[0] = 1.0f;
#pragma unroll
    for (int d = 1; d <= 5; ++d) wv[d] = w[d - 1];   // exp(-d/2)

    // ring of 11 accumulators x 4 columns; slot(o) = (o - t0) mod 11
    float acc[11][4];
#pragma unroll
    for (int i = 0; i < 11; ++i)
#pragma unroll
        for (int c = 0; c < 4; ++c) acc[i][c] = 0.0f;

    // preload first input row (t0 - 5)
    float  curL, curR;
    float4 curA, curB, curC;
    {
        const float* srow = s + (((t0 - 5) & GMASK) << 12);
        curL = srow[cm5];
        curA = *(const float4*)(srow + cm4);
        curB = *(const float4*)(srow + j0);
        curC = *(const float4*)(srow + cp4);
        curR = srow[cp8];
    }

#pragma unroll 1
    for (int it = 0; it < NITER; ++it) {
        const int tbase = t0 - 5 + it * 11;
#pragma unroll
        for (int ph = 0; ph < 11; ++ph) {
            // ---- prefetch row t+1 (overshoot on last phase is harmless, wraps) ----
            const int tn = tbase + ph + 1;
            const float* nrow = s + ((tn & GMASK) << 12);
            const float  nL = nrow[cm5];
            const float4 nA = *(const float4*)(nrow + cm4);
            const float4 nB = *(const float4*)(nrow + j0);
            const float4 nC = *(const float4*)(nrow + cp4);
            const float  nR = nrow[cp8];

            // ---- compute with current row t = tbase + ph ----
            float v[14];
            v[0] = curL;
            v[1] = curA.x; v[2]  = curA.y; v[3]  = curA.z; v[4]  = curA.w;
            v[5] = curB.x; v[6]  = curB.y; v[7]  = curB.z; v[8]  = curB.w;
            v[9] = curC.x; v[10] = curC.y; v[11] = curC.z; v[12] = curC.w;
            v[13] = curR;

#pragma unroll
            for (int c = 0; c < 4; ++c) {
                const float ctr = v[5 + c];
                float Hs[6];
                Hs[0] = ctr;
#pragma unroll
                for (int k = 1; k <= 5; ++k)
                    Hs[k] = Hs[k - 1] + wv[k] * (v[5 + c - k] + v[5 + c + k]);

                // scatter: row t contributes to output rows o = t+d, d = -5..5
                // slot(o) = (o - t0) mod 11 = (ph + d + 6) mod 11   (static)
                acc[(ph + 6) % 11][c] += Hs[5] - ctr;       // d = 0 (center removed)
#pragma unroll
                for (int d = 1; d <= 5; ++d) {
                    const float contrib = wv[d] * Hs[5 - d];
                    acc[(ph + d + 6) % 11][c] += contrib;   // d = +d
                    acc[(ph - d + 6) % 11][c] += contrib;   // d = -d
                }
            }

            // ---- output row o = t - 5 is complete (last contributor is t) ----
            {
                const int o  = tbase + ph - 5;
                const int sl = (ph + 1) % 11;               // = (o - t0) mod 11
                if (o >= t0 && o < GH) {
                    float4 r;
                    r.x = acc[sl][0]; r.y = acc[sl][1];
                    r.z = acc[sl][2]; r.w = acc[sl][3];
                    *(float4*)(out + ((size_t)o << 12) + j0) = r;
                }
                // always clear: slot is recycled for row o+11 starting next input row
                acc[sl][0] = 0.0f; acc[sl][1] = 0.0f;
                acc[sl][2] = 0.0f; acc[sl][3] = 0.0f;
            }

            // ---- rotate prefetched row into current ----
            curL = nL; curA = nA; curB = nB; curC = nC; curR = nR;
        }
    }
}

extern "C" void kernel_launch(void* const* d_in, const int* in_sizes, int n_in,
                              void* d_out, int out_size, void* d_ws, size_t ws_size,
                              hipStream_t stream)
{
    const float* s = (const float*)d_in[0];   // grid_spikes [4096*4096] f32
    const float* w = (const float*)d_in[1];   // distance_weights [5] f32
    float* out = (float*)d_out;               // [4096*4096] f32

    dim3 grid(8, (GH + RCHUNK - 1) / RCHUNK);  // 8 strips x 342 chunks = 2736 blocks
    dim3 block(128);
    diamond_stencil<<<grid, block, 0, stream>>>(s, w, out);
}

// Round 4
// 154.432 us; speedup vs baseline: 2.7787x; 1.0439x over previous
//
#include <hip/hip_runtime.h>

// LocalConnectivity: out[i][j] = sum_{1<=|dx|+|dy|<=5} w_{|dx|+|dy|} * s[(i+dx)&4095][(j+dy)&4095]
// w_d = exp(-d/2) = r^d  =>  separable: w_{|dx|+|dy|} = r^|dx| * r^|dy|
//
// out[i][j] = sum_{dx=-5..5} r^|dx| * H_{5-|dx|}[i+dx][j] - s[i][j]
// H_k built incrementally per row (5 add + 5 fma per column).
//
// R4 vs R3: R1/R3 showed grid-size-invariant ~75 us, VALUBusy 17%, 1.4 TB/s --
// a per-wave latency chain (one row's loads -> compute -> next row). Fix: batch
// 4 rows of loads (20 loads in flight), double-buffered so batch b+1 is in
// flight during batch b's compute (4 phases ~ 1080 cyc > 900 cyc HBM latency).
// 44 rows = 11 batches x 4 keeps ring-slot mod-11 indices compile-time static.

#define GH 4096
#define GMASK 4095
#define RCHUNK 34   // outputs per block; processes 44 = 11*4 input rows

__global__ __launch_bounds__(128)
void diamond_stencil(const float* __restrict__ s, const float* __restrict__ w,
                     float* __restrict__ out)
{
    const int tid   = threadIdx.x;
    const int strip = blockIdx.x;            // 0..7   -> 512-wide column strip
    const int chunk = blockIdx.y;            // 0..120 -> 34-row chunk
    const int j0 = strip * 512 + tid * 4;    // first of this thread's 4 columns
    const int t0 = chunk * RCHUNK;           // first output row of this chunk

    // wrapped column offsets; float4 bases stay 16B-aligned
    const int cm5 = (j0 - 5) & GMASK;
    const int cm4 = (j0 - 4) & GMASK;
    const int cp4 = (j0 + 4) & GMASK;
    const int cp8 = (j0 + 8) & GMASK;

    float wv[6];
    wv[0] = 1.0f;
#pragma unroll
    for (int d = 1; d <= 5; ++d) wv[d] = w[d - 1];   // exp(-d/2)

    // ring of 11 accumulators x 4 columns; slot(o) = (o - t0) mod 11
    float acc[11][4];
#pragma unroll
    for (int i = 0; i < 11; ++i)
#pragma unroll
        for (int c = 0; c < 4; ++c) acc[i][c] = 0.0f;

    // double-buffered 4-row load batches (raw values, unpacked at compute time)
    float4 bA[2][4], bB[2][4], bC[2][4];
    float  bL[2][4], bR[2][4];

    auto loadBatch = [&](int bsel, int g0) {
#pragma unroll
        for (int r = 0; r < 4; ++r) {
            const float* srow = s + (((t0 - 5 + g0 + r) & GMASK) << 12);
            bL[bsel][r] = srow[cm5];
            bA[bsel][r] = *(const float4*)(srow + cm4);
            bB[bsel][r] = *(const float4*)(srow + j0);
            bC[bsel][r] = *(const float4*)(srow + cp4);
            bR[bsel][r] = srow[cp8];
        }
    };

    loadBatch(0, 0);   // rows t0-5 .. t0-2

#pragma unroll
    for (int b = 0; b < 11; ++b) {
        if (b < 10) loadBatch((b + 1) & 1, 4 * (b + 1));   // prefetch next batch
        const int bs = b & 1;

#pragma unroll
        for (int p = 0; p < 4; ++p) {
            const int g = 4 * b + p;          // global phase 0..43; row t = t0-5+g

            float v[14];
            v[0]  = bL[bs][p];
            v[1]  = bA[bs][p].x; v[2]  = bA[bs][p].y; v[3]  = bA[bs][p].z; v[4]  = bA[bs][p].w;
            v[5]  = bB[bs][p].x; v[6]  = bB[bs][p].y; v[7]  = bB[bs][p].z; v[8]  = bB[bs][p].w;
            v[9]  = bC[bs][p].x; v[10] = bC[bs][p].y; v[11] = bC[bs][p].z; v[12] = bC[bs][p].w;
            v[13] = bR[bs][p];

#pragma unroll
            for (int c = 0; c < 4; ++c) {
                const float ctr = v[5 + c];
                float Hs[6];
                Hs[0] = ctr;
#pragma unroll
                for (int k = 1; k <= 5; ++k)
                    Hs[k] = Hs[k - 1] + wv[k] * (v[5 + c - k] + v[5 + c + k]);

                // row t contributes to output rows o = t+d, d = -5..5
                // slot(o) = (o - t0) mod 11 = (g + d + 6) mod 11  (compile-time)
                acc[(g + 6) % 11][c] += Hs[5] - ctr;        // d = 0 (center removed)
#pragma unroll
                for (int d = 1; d <= 5; ++d) {
                    const float contrib = wv[d] * Hs[5 - d];
                    acc[(g + d + 6) % 11][c] += contrib;    // d = +d
                    acc[(g - d + 6) % 11][c] += contrib;    // d = -d (g-d+6 >= 1)
                }
            }

            // output row o = t - 5 = t0 + g - 10 complete (last contributor is t)
            {
                const int o  = t0 + g - 10;
                const int sl = (g + 1) % 11;                // = (o - t0) mod 11
                if (g >= 10 && o < GH) {                    // g>=10 folds statically
                    float4 r;
                    r.x = acc[sl][0]; r.y = acc[sl][1];
                    r.z = acc[sl][2]; r.w = acc[sl][3];
                    *(float4*)(out + ((size_t)o << 12) + j0) = r;
                }
                // always clear: slot recycles for row o+11 starting next phase
                acc[sl][0] = 0.0f; acc[sl][1] = 0.0f;
                acc[sl][2] = 0.0f; acc[sl][3] = 0.0f;
            }
        }
    }
}

extern "C" void kernel_launch(void* const* d_in, const int* in_sizes, int n_in,
                              void* d_out, int out_size, void* d_ws, size_t ws_size,
                              hipStream_t stream)
{
    const float* s = (const float*)d_in[0];   // grid_spikes [4096*4096] f32
    const float* w = (const float*)d_in[1];   // distance_weights [5] f32
    float* out = (float*)d_out;               // [4096*4096] f32

    dim3 grid(8, (GH + RCHUNK - 1) / RCHUNK);  // 8 strips x 121 chunks = 968 blocks
    dim3 block(128);
    diamond_stencil<<<grid, block, 0, stream>>>(s, w, out);
}

// Round 6
// 152.911 us; speedup vs baseline: 2.8064x; 1.0099x over previous
//
#include <hip/hip_runtime.h>
#include <stdint.h>

// LocalConnectivity: out[i][j] = sum_{1<=|dx|+|dy|<=5} w_{|dx|+|dy|} * s[(i+dx)&4095][(j+dy)&4095]
// w_d = exp(-d/2) = r^d  =>  separable: w_{|dx|+|dy|} = r^|dx| * r^|dy|
// out[i][j] = sum_{dx=-5..5} r^|dx| * H_{5-|dx|}[i+dx][j] - s[i][j]
//
// R6 = R5 (per-wave global_load_lds pipeline, no __syncthreads) with the LDS
// slot-recycle race closed:
//  - PF 7->5: slot reuse distance = NBUF-PF = 3 iterations (was 1)
//  - s_waitcnt lgkmcnt(0) before each issueRow: all prior ds_reads retired
//    before any DMA that could overwrite their slot is issued
//  - sched_barrier(0) pins the order: [lgkm fence, issue, vmcnt drain] | ds_reads
// Write-before-read: row i's loads have >=3*PF=15 newer vmem ops at the drain
// (stores are newer still, only add slack) -> vmcnt(15) is always sufficient.

#define GH     4096
#define GMASK  4095
#define RCHUNK 23          // outputs per chunk; processes 33 = 3*11 rows
#define NROWS  33
#define PF     5           // prefetch distance (rows in flight)
#define NBUF   8           // LDS slots per wave (power of 2)
#define SLOT   288         // floats per slot (272 used: 8 halo + 256 + 8 halo)

// s_waitcnt imm (gfx9): vmcnt[3:0]=bits[3:0], vmcnt[5:4]=bits[15:14],
// expcnt=bits[6:4], lgkmcnt=bits[11:8].
#define WAIT_VM15 ((15 & 15) | ((15 >> 4) << 14) | (7 << 4) | (15 << 8))  // vmcnt(15), rest no-wait
#define WAIT_LGKM0 ((63 & 15) | ((63 >> 4) << 14) | (7 << 4) | (0 << 8)) // lgkmcnt(0), rest no-wait

// global -> LDS direct DMA. LDS dst = wave-uniform base + lane*size.
#define GLOAD_LDS(gp, lp, sz)                                                   \
    __builtin_amdgcn_global_load_lds(                                           \
        (__attribute__((address_space(1))) void*)(uintptr_t)(gp),               \
        (__attribute__((address_space(3))) void*)(uint32_t)(uintptr_t)(lp),     \
        (sz), 0, 0)

__global__ __launch_bounds__(256)
void diamond_stencil(const float* __restrict__ s, const float* __restrict__ w,
                     float* __restrict__ out)
{
    __shared__ __align__(16) float ldsbuf[4 * NBUF * SLOT];   // 36864 B

    const int tid   = threadIdx.x;
    const int lane  = tid & 63;
    const int wvid  = tid >> 6;                  // 0..3, each wave independent
    const int strip = (blockIdx.x << 2) + wvid;  // 0..15 -> 256-col strip
    const int c0    = strip << 8;
    const int t0    = blockIdx.y * RCHUNK;

    float* myLds = ldsbuf + wvid * (NBUF * SLOT);

    const int colMain = c0 + (lane << 2);              // 4 floats via width-16 DMA
    const int colL    = (c0 - 8 + lane) & GMASK;       // lanes 0..7: left halo
    const int colR    = (c0 + 256 + lane) & GMASK;     // lanes 0..7: right halo

    float wgt[6];
    wgt[0] = 1.0f;
#pragma unroll
    for (int d = 1; d <= 5; ++d) wgt[d] = w[d - 1];    // exp(-d/2)

    // ring of 11 accumulators x 4 columns; slot(o) = (o - t0) mod 11
    float acc[11][4];
#pragma unroll
    for (int i = 0; i < 11; ++i)
#pragma unroll
        for (int c = 0; c < 4; ++c) acc[i][c] = 0.0f;

    // stage row (t0 - 5 + i) into LDS slot i % NBUF:
    // layout: [0..7] left halo, [8..263] main, [264..271] right halo
    auto issueRow = [&](int i) {
        const int row = (t0 - 5 + i) & GMASK;
        const float* rp = s + ((size_t)row << 12);
        float* slot = myLds + (i & (NBUF - 1)) * SLOT;
        GLOAD_LDS(rp + colMain, slot + 8, 16);         // 64 lanes x 16B
        if (lane < 8) {
            GLOAD_LDS(rp + colL, slot, 4);             // 8 lanes x 4B
            GLOAD_LDS(rp + colR, slot + 264, 4);       // 8 lanes x 4B
        }
    };

#pragma unroll
    for (int i = 0; i < PF; ++i) issueRow(i);          // fill pipeline: rows 0..4

#pragma unroll
    for (int i = 0; i < NROWS; ++i) {
        // ---- ordered memory sequence ----
        __builtin_amdgcn_sched_barrier(0);
        // all prior ds_reads retired -> safe to issue DMA that recycles a slot
        __builtin_amdgcn_s_waitcnt(WAIT_LGKM0);
        issueRow(i + PF);                              // overshoot wraps; harmless
        // row i's loads have >=15 newer vmem ops -> vmcnt(15) completes them
        __builtin_amdgcn_s_waitcnt(WAIT_VM15);
        __builtin_amdgcn_sched_barrier(0);

        // lane window: cols c0+4*lane-5 .. +8 -> slot floats 4*lane+3 .. 4*lane+16
        const float* sp = myLds + (i & (NBUF - 1)) * SLOT + (lane << 2);
        const float4 q0 = *(const float4*)(sp + 0);
        const float4 q1 = *(const float4*)(sp + 4);
        const float4 q2 = *(const float4*)(sp + 8);
        const float4 q3 = *(const float4*)(sp + 12);
        const float4 q4 = *(const float4*)(sp + 16);

        float v[14];
        v[0]  = q0.w;
        v[1]  = q1.x; v[2]  = q1.y; v[3]  = q1.z; v[4]  = q1.w;
        v[5]  = q2.x; v[6]  = q2.y; v[7]  = q2.z; v[8]  = q2.w;
        v[9]  = q3.x; v[10] = q3.y; v[11] = q3.z; v[12] = q3.w;
        v[13] = q4.x;

#pragma unroll
        for (int c = 0; c < 4; ++c) {
            const float ctr = v[5 + c];
            float Hs[6];
            Hs[0] = ctr;
#pragma unroll
            for (int k = 1; k <= 5; ++k)
                Hs[k] = Hs[k - 1] + wgt[k] * (v[5 + c - k] + v[5 + c + k]);

            // row t = t0-5+i -> outputs o = t+d, d=-5..5
            // slot(o) = (o - t0) mod 11 = (i + d + 6) mod 11  (compile-time)
            acc[(i + 6) % 11][c] += Hs[5] - ctr;       // d = 0 (center removed)
#pragma unroll
            for (int d = 1; d <= 5; ++d) {
                const float contrib = wgt[d] * Hs[5 - d];
                acc[(i + d + 6) % 11][c] += contrib;   // d = +d
                acc[(i - d + 6) % 11][c] += contrib;   // d = -d
            }
        }

        // output row o = t - 5 = t0 + i - 10 complete (last contributor is t)
        {
            const int o  = t0 + i - 10;
            const int sl = (i + 1) % 11;               // = (o - t0) mod 11
            if (i >= 10 && o < GH) {                   // i>=10 folds statically
                float4 r;
                r.x = acc[sl][0]; r.y = acc[sl][1];
                r.z = acc[sl][2]; r.w = acc[sl][3];
                *(float4*)(out + ((size_t)o << 12) + colMain) = r;
            }
            // always clear: slot recycles for row o+11 starting next phase
            acc[sl][0] = 0.0f; acc[sl][1] = 0.0f;
            acc[sl][2] = 0.0f; acc[sl][3] = 0.0f;
        }
    }
}

extern "C" void kernel_launch(void* const* d_in, const int* in_sizes, int n_in,
                              void* d_out, int out_size, void* d_ws, size_t ws_size,
                              hipStream_t stream)
{
    const float* s = (const float*)d_in[0];   // grid_spikes [4096*4096] f32
    const float* w = (const float*)d_in[1];   // distance_weights [5] f32
    float* out = (float*)d_out;               // [4096*4096] f32

    dim3 grid(4, (GH + RCHUNK - 1) / RCHUNK);  // 4 x 179 = 716 blocks (2864 waves)
    dim3 block(256);
    diamond_stencil<<<grid, block, 0, stream>>>(s, w, out);
}

// Round 7
// 152.806 us; speedup vs baseline: 2.8083x; 1.0007x over previous
//
#include <hip/hip_runtime.h>

// LocalConnectivity: out[i][j] = sum_{1<=|dx|+|dy|<=5} w_{|dx|+|dy|} * s[(i+dx)&4095][(j+dy)&4095]
// w_d = exp(-d/2) = r^d  =>  separable per diagonal: w_{|dx|+|dy|} = r^|dx| * r^|dy|
// out[i][j] = sum_{dx=-5..5} r^|dx| * H_{5-|dx|}[i+dx][j] - s[i][j]
// H_k[t][j] = sum_{|dy|<=k} r^|dy| s[t][j+dy]  (incremental: 5 add + 5 fma)
//
// R7: all prior rounds (register ring, batched ILP, async LDS pipeline) plateaued
// at ~70 us = 1.8 TB/s = only ~4 KB in flight per CU (latency-bound, Little's law).
// Compiler defeats ILP depth; so go pure TLP: thread computes a 4x8 output patch
// from 14 streamed rows, low VGPR (~80) -> 20-24 resident waves/CU (2x prior),
// short 14-row chain, 8192 waves total. No LDS, no manual waitcnt.

#define GH     4096
#define GMASK  4095
#define RCHUNK 4           // output rows per thread
#define NR     (RCHUNK + 10)   // 14 input rows streamed

__global__ __launch_bounds__(256)
void diamond_stencil(const float* __restrict__ s, const float* __restrict__ w,
                     float* __restrict__ out)
{
    const int tid = threadIdx.x;
    const int j0  = blockIdx.x * 2048 + tid * 8;   // 8 columns per thread, 32B-aligned
    const int t0  = blockIdx.y * RCHUNK;           // 4 output rows per thread

    // wrapped column bases (all float4 bases stay 16B-aligned; wrap only at strip edges)
    const int cL  = (j0 - 5) & GMASK;              // scalar left halo
    const int cm4 = (j0 - 4) & GMASK;
    const int cp8 = (j0 + 8) & GMASK;
    const int cR  = (j0 + 12) & GMASK;             // scalar right halo

    float wgt[6];
    wgt[0] = 1.0f;
#pragma unroll
    for (int d = 1; d <= 5; ++d) wgt[d] = w[d - 1];   // exp(-d/2)

    float acc[RCHUNK][8];
#pragma unroll
    for (int a = 0; a < RCHUNK; ++a)
#pragma unroll
        for (int c = 0; c < 8; ++c) acc[a][c] = 0.0f;

#pragma unroll
    for (int r = 0; r < NR; ++r) {
        const float* row = s + ((size_t)((t0 - 5 + r) & GMASK) << 12);

        // 18 floats: cols j0-5 .. j0+12 (6 independent loads, hoistable)
        float v[18];
        v[0] = row[cL];
        const float4 A = *(const float4*)(row + cm4);
        const float4 B = *(const float4*)(row + j0);
        const float4 C = *(const float4*)(row + j0 + 4);
        const float4 D = *(const float4*)(row + cp8);
        v[17] = row[cR];
        v[1]  = A.x; v[2]  = A.y; v[3]  = A.z; v[4]  = A.w;
        v[5]  = B.x; v[6]  = B.y; v[7]  = B.z; v[8]  = B.w;
        v[9]  = C.x; v[10] = C.y; v[11] = C.z; v[12] = C.w;
        v[13] = D.x; v[14] = D.y; v[15] = D.z; v[16] = D.w;

#pragma unroll
        for (int c = 0; c < 8; ++c) {
            const float ctr = v[5 + c];
            float Hs[6];
            Hs[0] = ctr;
#pragma unroll
            for (int k = 1; k <= 5; ++k)
                Hs[k] = Hs[k - 1] + wgt[k] * (v[5 + c - k] + v[5 + c + k]);

            // input row t = t0-5+r contributes to output row o = t0+a iff |r-5-a| <= 5
#pragma unroll
            for (int a = 0; a < RCHUNK; ++a) {
                const int d = r - 5 - a;               // compile-time
                if (d < -5 || d > 5) continue;
                if (d == 0)
                    acc[a][c] += Hs[5] - ctr;          // center excluded
                else {
                    const int ad = d < 0 ? -d : d;
                    acc[a][c] += wgt[ad] * Hs[5 - ad];
                }
            }
        }
    }

    // store 4 rows x 8 cols (two aligned float4 per row; j0+7 <= 4095, no wrap)
#pragma unroll
    for (int a = 0; a < RCHUNK; ++a) {
        float* op = out + ((size_t)(t0 + a) << 12) + j0;
        float4 r0, r1;
        r0.x = acc[a][0]; r0.y = acc[a][1]; r0.z = acc[a][2]; r0.w = acc[a][3];
        r1.x = acc[a][4]; r1.y = acc[a][5]; r1.z = acc[a][6]; r1.w = acc[a][7];
        *(float4*)(op)     = r0;
        *(float4*)(op + 4) = r1;
    }
}

extern "C" void kernel_launch(void* const* d_in, const int* in_sizes, int n_in,
                              void* d_out, int out_size, void* d_ws, size_t ws_size,
                              hipStream_t stream)
{
    const float* s = (const float*)d_in[0];   // grid_spikes [4096*4096] f32
    const float* w = (const float*)d_in[1];   // distance_weights [5] f32
    float* out = (float*)d_out;               // [4096*4096] f32

    // 2 x-strips (2048 cols = 256 thr x 8) x 1024 row-chunks = 2048 blocks, 8192 waves
    dim3 grid(2, GH / RCHUNK);
    dim3 block(256);
    diamond_stencil<<<grid, block, 0, stream>>>(s, w, out);
}